// Round 8
// baseline (234.816 us; speedup 1.0000x reference)
//
#include <hip/hip_runtime.h>

#define NB    131072   // batch rows
#define TPB   512      // 8 waves/block
#define NBLK  512      // 2 blocks/CU
#define TILES 4        // 64-row tiles per block (512*4*64 = NB)
#define FANIN 260

__device__ __forceinline__ float sigm_(float x) { return 1.0f / (1.0f + __expf(-x)); }
__device__ __forceinline__ float tanh_(float x) { return 1.0f - 2.0f / (__expf(2.0f * x) + 1.0f); }

__device__ __forceinline__ void gld_lds16(const float4* g, float4* l) {
    __builtin_amdgcn_global_load_lds(
        (const __attribute__((address_space(1))) void*)g,
        (__attribute__((address_space(3))) void*)l, 16, 0, 0);
}

// Repack weights k-major Wp[k][16] (gw=g*4+w), bth = bias+theta.
// ws re-poison is UNCONDITIONAL (measured r1) -> ws use is free.
__global__ void qlstm_prep(const float* __restrict__ Wf, const float* __restrict__ bf,
                           const float* __restrict__ Wi, const float* __restrict__ bi,
                           const float* __restrict__ Wu, const float* __restrict__ bu,
                           const float* __restrict__ Wo, const float* __restrict__ bo,
                           const float* __restrict__ thf, const float* __restrict__ thi,
                           const float* __restrict__ thu, const float* __restrict__ tho,
                           float* __restrict__ Wp, float* __restrict__ bth) {
    int t = blockIdx.x * blockDim.x + threadIdx.x;
    if (t < FANIN * 16) {
        int k = t >> 4, gw = t & 15, g = gw >> 2, w = gw & 3;
        const float* Wg = (g == 0) ? Wf : (g == 1) ? Wi : (g == 2) ? Wu : Wo;
        Wp[t] = Wg[w * FANIN + k];
    }
    if (t < 16) {
        int g = t >> 2, w = t & 3;
        const float* bg = (g == 0) ? bf  : (g == 1) ? bi  : (g == 2) ? bu  : bo;
        const float* tg = (g == 0) ? thf : (g == 1) ? thi : (g == 2) ? thu : tho;
        bth[t] = bg[w] + tg[w];
    }
}

// Hot kernel: x-GEMV only (k 0..255). Steady-state T3/T4 pipeline:
// unit = 64 rows x 16 f4cols = 16 KB; compute unit u while unit u+1's
// global_load_lds are in flight; counted vmcnt, never 0.
__global__ __launch_bounds__(TPB, 4) void qlstm_gemv(
        const float* __restrict__ x, const float* __restrict__ Wp,
        float4* __restrict__ wsAcc /* [4][NB] transposed acc store */) {
    __shared__ float4 xb0[64 * 16];     // 16 KB, parity-0 unit buffer
    __shared__ float4 xb1[64 * 16];     // 16 KB, parity-1 unit buffer
    __shared__ float4 ex4[4 * 4 * 64];  // 16 KB reduce exchange [j4][srcw][lane]

    const int tid  = threadIdx.x;
    const int lane = tid & 63;
    const int wvu  = __builtin_amdgcn_readfirstlane(tid >> 6);
    const int brow0 = blockIdx.x * (TILES * 64);

    const float4* x4 = (const float4*)x;

    // Staging geometry (unit-invariant). Instr ii in {0,1} covers rows
    // rii = 4*(wvu*2+ii) + (lane>>4); 16 lanes per row-segment (256 B).
    // Global col pre-swizzled (rule 21): c = (lane&15) ^ (r&7) -> LDS slot
    // (r*16 + t) holds col (t ^ (r&7)); read back with the same XOR.
    const int r0 = 4 * (wvu * 2 + 0) + (lane >> 4);
    const int r1 = 4 * (wvu * 2 + 1) + (lane >> 4);
    const int c0 = (lane & 15) ^ (r0 & 7);
    const int c1 = (lane & 15) ^ (r1 & 7);

#define ISSUE_UNIT(TT, QQ, DST) do {                                                   \
        gld_lds16(x4 + (size_t)(brow0 + (TT) * 64 + r0) * 64 + (QQ) * 16 + c0,         \
                  &(DST)[(wvu * 2 + 0) * 64]);                                         \
        gld_lds16(x4 + (size_t)(brow0 + (TT) * 64 + r1) * 64 + (QQ) * 16 + c1,         \
                  &(DST)[(wvu * 2 + 1) * 64]);                                         \
    } while (0)

    // Prologue: units 0 and 1 in flight.
    ISSUE_UNIT(0, 0, xb0);
    ISSUE_UNIT(0, 1, xb1);

    float acc[16];
#pragma unroll
    for (int j = 0; j < 16; ++j) acc[j] = 0.0f;

    for (int tau = 0; tau < TILES; ++tau) {
#pragma unroll
        for (int q = 0; q < 4; ++q) {
            // Counted wait: current unit's 2 loads retired, next unit's 2 stay
            // in flight. Wave0 additionally carries 4 in-order acc-stores from
            // the previous tile across the first two units -> vmcnt(6) there.
            if (q < 2 && wvu == 0 && tau > 0)
                asm volatile("s_waitcnt vmcnt(6)" ::: "memory");
            else
                asm volatile("s_waitcnt vmcnt(2)" ::: "memory");
            __builtin_amdgcn_s_barrier();   // all waves' unit-u data visible

            const float4* pb = (q & 1) ? xb1 : xb0;
#pragma unroll
            for (int j = 0; j < 2; ++j) {
                // conflict-free ds_read_b128 through the XOR swizzle
                float4 xv = pb[lane * 16 + ((wvu * 2 + j) ^ (lane & 7))];
                const float* wp = Wp + (q * 16 + wvu * 2 + j) * 64;  // s_load, 64 B rows
#pragma unroll
                for (int m = 0; m < 4; ++m) {
                    float xe = (m == 0) ? xv.x : (m == 1) ? xv.y
                             : (m == 2) ? xv.z : xv.w;
#pragma unroll
                    for (int jj = 0; jj < 16; ++jj)
                        acc[jj] = fmaf(xe, wp[m * 16 + jj], acc[jj]);
                }
            }
            __builtin_amdgcn_s_barrier();   // reads of this buffer done block-wide
            if (tau < TILES - 1 || q < 2) {
                const int u2 = tau * 4 + q + 2;
                if (q & 1) ISSUE_UNIT(u2 >> 2, u2 & 3, xb1);
                else       ISSUE_UNIT(u2 >> 2, u2 & 3, xb0);
            }
        }

        // ---- per-tile cross-wave reduce (2-stage tree) + transposed store ----
        if (wvu >= 4) {
#pragma unroll
            for (int j4 = 0; j4 < 4; ++j4)
                ex4[(j4 * 4 + (wvu - 4)) * 64 + lane] =
                    make_float4(acc[j4 * 4 + 0], acc[j4 * 4 + 1],
                                acc[j4 * 4 + 2], acc[j4 * 4 + 3]);
        }
        __builtin_amdgcn_s_barrier();
        if (wvu < 4) {
#pragma unroll
            for (int j4 = 0; j4 < 4; ++j4) {
                float4 p = ex4[(j4 * 4 + wvu) * 64 + lane];
                acc[j4 * 4 + 0] += p.x; acc[j4 * 4 + 1] += p.y;
                acc[j4 * 4 + 2] += p.z; acc[j4 * 4 + 3] += p.w;
            }
        }
        if (wvu >= 1 && wvu < 4) {
#pragma unroll
            for (int j4 = 0; j4 < 4; ++j4)
                ex4[(j4 * 4 + wvu) * 64 + lane] =
                    make_float4(acc[j4 * 4 + 0], acc[j4 * 4 + 1],
                                acc[j4 * 4 + 2], acc[j4 * 4 + 3]);
        }
        __builtin_amdgcn_s_barrier();
        if (wvu == 0) {
#pragma unroll
            for (int j4 = 0; j4 < 4; ++j4) {
                float4 p1 = ex4[(j4 * 4 + 1) * 64 + lane];
                float4 p2 = ex4[(j4 * 4 + 2) * 64 + lane];
                float4 p3 = ex4[(j4 * 4 + 3) * 64 + lane];
                wsAcc[(size_t)j4 * NB + brow0 + tau * 64 + lane] =
                    make_float4(acc[j4 * 4 + 0] + p1.x + p2.x + p3.x,
                                acc[j4 * 4 + 1] + p1.y + p2.y + p3.y,
                                acc[j4 * 4 + 2] + p1.z + p2.z + p3.z,
                                acc[j4 * 4 + 3] + p1.w + p2.w + p3.w);
            }
        }
#pragma unroll
        for (int j = 0; j < 16; ++j) acc[j] = 0.0f;
    }
#undef ISSUE_UNIT
}

// Cold tail: hx GEMV tail + quantum-gate closed form + LSTM epilogue (~14 MB).
__global__ __launch_bounds__(256) void qlstm_tail(
        const float4* __restrict__ wsAcc, const float* __restrict__ hx,
        const float* __restrict__ cx, const float* __restrict__ Wp,
        const float* __restrict__ bth, float* __restrict__ out) {
    const int row = blockIdx.x * 256 + threadIdx.x;

    float acc[16];
#pragma unroll
    for (int j4 = 0; j4 < 4; ++j4) {
        float4 a = wsAcc[(size_t)j4 * NB + row];   // coalesced (transposed layout)
        acc[j4 * 4 + 0] = a.x; acc[j4 * 4 + 1] = a.y;
        acc[j4 * 4 + 2] = a.z; acc[j4 * 4 + 3] = a.w;
    }

    float4 hv = ((const float4*)hx)[row];
    {
        const float* wp = Wp + 256 * 16;
#pragma unroll
        for (int j = 0; j < 16; ++j) acc[j] = fmaf(hv.x, wp[j],      acc[j]);
#pragma unroll
        for (int j = 0; j < 16; ++j) acc[j] = fmaf(hv.y, wp[16 + j], acc[j]);
#pragma unroll
        for (int j = 0; j < 16; ++j) acc[j] = fmaf(hv.z, wp[32 + j], acc[j]);
#pragma unroll
        for (int j = 0; j < 16; ++j) acc[j] = fmaf(hv.w, wp[48 + j], acc[j]);
    }

    // c_w = cos(angle + b + th); E0=c1*c2*c3, E1=c0*c1, E2=c0*c1*c2, E3=c0*c1*c2*c3
    float co[16];
#pragma unroll
    for (int j = 0; j < 16; ++j) co[j] = __cosf(acc[j] + bth[j]);

    float G[16];
#pragma unroll
    for (int g = 0; g < 4; ++g) {
        float c0 = co[g * 4 + 0], c1 = co[g * 4 + 1];
        float c2 = co[g * 4 + 2], c3 = co[g * 4 + 3];
        float e1 = c0 * c1;
        float e2 = e1 * c2;
        float e3 = e2 * c3;
        float e0 = c1 * c2 * c3;
        G[g * 4 + 0] = e0; G[g * 4 + 1] = e1; G[g * 4 + 2] = e2; G[g * 4 + 3] = e3;
    }

    float4 cxv = ((const float4*)cx)[row];
    float cxa[4] = {cxv.x, cxv.y, cxv.z, cxv.w};
    float hn[4], cn[4];
#pragma unroll
    for (int w = 0; w < 4; ++w) {
        float fg = sigm_(G[0 * 4 + w]);
        float ig = sigm_(G[1 * 4 + w]);
        float ug = tanh_(G[2 * 4 + w]);
        float og = sigm_(G[3 * 4 + w]);
        float c_ = fg * cxa[w] + ig * ug;
        cn[w] = c_;
        hn[w] = og * tanh_(c_);
    }

    ((float4*)out)[row]      = make_float4(hn[0], hn[1], hn[2], hn[3]);  // h_new
    ((float4*)out)[NB + row] = make_float4(cn[0], cn[1], cn[2], cn[3]);  // c_new
}

extern "C" void kernel_launch(void* const* d_in, const int* in_sizes, int n_in,
                              void* d_out, int out_size, void* d_ws, size_t ws_size,
                              hipStream_t stream) {
    const float* x   = (const float*)d_in[0];
    const float* hx  = (const float*)d_in[1];
    const float* cx  = (const float*)d_in[2];
    const float* Wf  = (const float*)d_in[3];
    const float* bf  = (const float*)d_in[4];
    const float* Wi  = (const float*)d_in[5];
    const float* bi  = (const float*)d_in[6];
    const float* Wu  = (const float*)d_in[7];
    const float* bu  = (const float*)d_in[8];
    const float* Wo  = (const float*)d_in[9];
    const float* bo  = (const float*)d_in[10];
    const float* thf = (const float*)d_in[11];
    const float* thi = (const float*)d_in[12];
    const float* thu = (const float*)d_in[13];
    const float* tho = (const float*)d_in[14];

    float*  Wp    = (float*)d_ws;                         // 16640 B
    float*  bth   = Wp + FANIN * 16;                      // 64 B
    float4* wsAcc = (float4*)((char*)d_ws + 32768);       // 8 MB [4][NB]

    qlstm_prep<<<(FANIN * 16 + 255) / 256, 256, 0, stream>>>(
        Wf, bf, Wi, bi, Wu, bu, Wo, bo, thf, thi, thu, tho, Wp, bth);

    qlstm_gemv<<<NBLK, TPB, 0, stream>>>(x, Wp, wsAcc);

    qlstm_tail<<<NB / 256, 256, 0, stream>>>(wsAcc, hx, cx, Wp, bth, (float*)d_out);
}